// Round 1
// baseline (1728.785 us; speedup 1.0000x reference)
//
#include <hip/hip_runtime.h>

#define N_NODES 100000
#define N_EDGES 1600000
#define NEG_SLOPE 0.2f

// ---------- helpers ----------
__device__ __forceinline__ float leaky(float v) { return v >= 0.f ? v : NEG_SLOPE * v; }

// monotonic float<->uint mapping for atomicMax on floats.
// memset-0 init decodes to -NaN sentinel (< everything); every node has a
// self-loop so every m slot gets written.
__device__ __forceinline__ unsigned fkey(float f) {
    unsigned u = __float_as_uint(f);
    return (u & 0x80000000u) ? ~u : (u | 0x80000000u);
}
__device__ __forceinline__ float kfloat(unsigned k) {
    return __uint_as_float((k & 0x80000000u) ? (k & 0x7FFFFFFFu) : ~k);
}

// ---------- K0: 20 per-head dot constants ----------
// consts[0..7]  : cS1[r][h] = dot(W1[r, h*32:(h+1)*32], attS1[h,:])   (r*4+h)
// consts[8..15] : cD1[r][h] same with attD1
// consts[16..19]: cE1[h]    = dot(We1[0, h*32:(h+1)*32], attE1[h,:])
__global__ void k_consts(const float* __restrict__ W1, const float* __restrict__ attS1,
                         const float* __restrict__ attD1, const float* __restrict__ We1,
                         const float* __restrict__ attE1, float* __restrict__ consts) {
    int t = threadIdx.x;
    if (t < 8) {
        int r = t >> 2, h = t & 3;
        float s = 0.f;
        for (int c = 0; c < 32; ++c) s += W1[r * 128 + h * 32 + c] * attS1[h * 32 + c];
        consts[t] = s;
    } else if (t < 16) {
        int u = t - 8, r = u >> 2, h = u & 3;
        float s = 0.f;
        for (int c = 0; c < 32; ++c) s += W1[r * 128 + h * 32 + c] * attD1[h * 32 + c];
        consts[t] = s;
    } else if (t < 20) {
        int h = t - 16;
        float s = 0.f;
        for (int c = 0; c < 32; ++c) s += We1[h * 32 + c] * attE1[h * 32 + c];
        consts[t] = s;
    }
}

// ---------- K1: in-degree count + incident-weight sum (original E edges only) ----------
__global__ void k_degree(const int* __restrict__ ei, const float* __restrict__ w,
                         float* __restrict__ cntf, float* __restrict__ wsum) {
    int stride = gridDim.x * blockDim.x;
    for (int e = blockIdx.x * blockDim.x + threadIdx.x; e < N_EDGES; e += stride) {
        int dst = ei[N_EDGES + e];
        atomicAdd(&cntf[dst], 1.f);
        atomicAdd(&wsum[dst], w[e]);
    }
}

// ---------- K2: per-node a_src/a_dst (4 heads) + self-loop attr ----------
__global__ void k_nodeA(const float* __restrict__ x, const float* __restrict__ consts,
                        const float* __restrict__ cntf, const float* __restrict__ wsum,
                        float* __restrict__ aS1, float* __restrict__ aD1,
                        float* __restrict__ loop_attr) {
    int stride = gridDim.x * blockDim.x;
    for (int n = blockIdx.x * blockDim.x + threadIdx.x; n < N_NODES; n += stride) {
        float x0 = x[2 * n], x1 = x[2 * n + 1];
#pragma unroll
        for (int h = 0; h < 4; ++h) {
            aS1[n * 4 + h] = x0 * consts[h] + x1 * consts[4 + h];
            aD1[n * 4 + h] = x0 * consts[8 + h] + x1 * consts[12 + h];
        }
        loop_attr[n] = wsum[n] / fmaxf(cntf[n], 1.f);
    }
}

// ---------- K3: layer-1 segment max over E real edges + N self-loops ----------
__global__ void k_max1(const int* __restrict__ ei, const float* __restrict__ w,
                       const float* __restrict__ aS1, const float* __restrict__ aD1,
                       const float* __restrict__ loop_attr, const float* __restrict__ consts,
                       unsigned* __restrict__ m1u) {
    int stride = gridDim.x * blockDim.x;
    float cE0 = consts[16], cE1 = consts[17], cE2 = consts[18], cE3 = consts[19];
    for (int e = blockIdx.x * blockDim.x + threadIdx.x; e < N_EDGES + N_NODES; e += stride) {
        int src, dst;
        float wt;
        if (e < N_EDGES) { src = ei[e]; dst = ei[N_EDGES + e]; wt = w[e]; }
        else             { src = dst = e - N_EDGES; wt = loop_attr[src]; }
        float4 as = *(const float4*)(aS1 + src * 4);
        float4 ad = *(const float4*)(aD1 + dst * 4);
        atomicMax(m1u + dst * 4 + 0, fkey(leaky(as.x + ad.x + wt * cE0)));
        atomicMax(m1u + dst * 4 + 1, fkey(leaky(as.y + ad.y + wt * cE1)));
        atomicMax(m1u + dst * 4 + 2, fkey(leaky(as.z + ad.z + wt * cE2)));
        atomicMax(m1u + dst * 4 + 3, fkey(leaky(as.w + ad.w + wt * cE3)));
    }
}

// ---------- K4: layer-1 exp + softmax denom + linearity-collapsed aggregation ----------
// out1[n,h,c] = (X0[n,h]*W1[0,hc] + X1[n,h]*W1[1,hc]) / (s[n,h]+1e-16)
__global__ void k_agg1(const int* __restrict__ ei, const float* __restrict__ w,
                       const float* __restrict__ x, const float* __restrict__ aS1,
                       const float* __restrict__ aD1, const float* __restrict__ loop_attr,
                       const float* __restrict__ consts, const unsigned* __restrict__ m1u,
                       float* __restrict__ s1, float* __restrict__ accX0,
                       float* __restrict__ accX1) {
    int stride = gridDim.x * blockDim.x;
    float cE0 = consts[16], cE1 = consts[17], cE2 = consts[18], cE3 = consts[19];
    for (int e = blockIdx.x * blockDim.x + threadIdx.x; e < N_EDGES + N_NODES; e += stride) {
        int src, dst;
        float wt;
        if (e < N_EDGES) { src = ei[e]; dst = ei[N_EDGES + e]; wt = w[e]; }
        else             { src = dst = e - N_EDGES; wt = loop_attr[src]; }
        float4 as = *(const float4*)(aS1 + src * 4);
        float4 ad = *(const float4*)(aD1 + dst * 4);
        uint4 mk = *(const uint4*)(m1u + dst * 4);
        float p0 = expf(leaky(as.x + ad.x + wt * cE0) - kfloat(mk.x));
        float p1 = expf(leaky(as.y + ad.y + wt * cE1) - kfloat(mk.y));
        float p2 = expf(leaky(as.z + ad.z + wt * cE2) - kfloat(mk.z));
        float p3 = expf(leaky(as.w + ad.w + wt * cE3) - kfloat(mk.w));
        float x0 = x[2 * src], x1 = x[2 * src + 1];
        atomicAdd(&s1[dst * 4 + 0], p0);
        atomicAdd(&s1[dst * 4 + 1], p1);
        atomicAdd(&s1[dst * 4 + 2], p2);
        atomicAdd(&s1[dst * 4 + 3], p3);
        atomicAdd(&accX0[dst * 4 + 0], p0 * x0);
        atomicAdd(&accX0[dst * 4 + 1], p1 * x0);
        atomicAdd(&accX0[dst * 4 + 2], p2 * x0);
        atomicAdd(&accX0[dst * 4 + 3], p3 * x0);
        atomicAdd(&accX1[dst * 4 + 0], p0 * x1);
        atomicAdd(&accX1[dst * 4 + 1], p1 * x1);
        atomicAdd(&accX1[dst * 4 + 2], p2 * x1);
        atomicAdd(&accX1[dst * 4 + 3], p3 * x1);
    }
}

// ---------- K5: reconstruct out1, +b1, ELU, matvec with W2 -> h2 scalar ----------
__global__ void k_node2(const float* __restrict__ accX0, const float* __restrict__ accX1,
                        const float* __restrict__ s1, const float* __restrict__ W1,
                        const float* __restrict__ b1, const float* __restrict__ W2,
                        float* __restrict__ h2) {
    int stride = gridDim.x * blockDim.x;
    for (int n = blockIdx.x * blockDim.x + threadIdx.x; n < N_NODES; n += stride) {
        float acc = 0.f;
#pragma unroll
        for (int h = 0; h < 4; ++h) {
            float X0 = accX0[n * 4 + h];
            float X1 = accX1[n * 4 + h];
            float inv = 1.f / (s1[n * 4 + h] + 1e-16f);
            for (int c = 0; c < 32; ++c) {
                int j = h * 32 + c;
                float v = (X0 * W1[j] + X1 * W1[128 + j]) * inv + b1[j];
                float el = v > 0.f ? v : expm1f(v);  // jax.nn.elu
                acc += el * W2[j];
            }
        }
        h2[n] = acc;
    }
}

// ---------- K6: layer-2 segment max ----------
__global__ void k_max2(const int* __restrict__ ei, const float* __restrict__ w,
                       const float* __restrict__ h2, const float* __restrict__ loop_attr,
                       const float* __restrict__ attS2, const float* __restrict__ attD2,
                       const float* __restrict__ We2, const float* __restrict__ attE2,
                       unsigned* __restrict__ m2u) {
    int stride = gridDim.x * blockDim.x;
    float aS = attS2[0], aD = attD2[0], cE = We2[0] * attE2[0];
    for (int e = blockIdx.x * blockDim.x + threadIdx.x; e < N_EDGES + N_NODES; e += stride) {
        int src, dst;
        float wt;
        if (e < N_EDGES) { src = ei[e]; dst = ei[N_EDGES + e]; wt = w[e]; }
        else             { src = dst = e - N_EDGES; wt = loop_attr[src]; }
        atomicMax(m2u + dst, fkey(leaky(h2[src] * aS + h2[dst] * aD + wt * cE)));
    }
}

// ---------- K7: layer-2 exp + denom + weighted aggregation ----------
__global__ void k_sum2(const int* __restrict__ ei, const float* __restrict__ w,
                       const float* __restrict__ h2, const float* __restrict__ loop_attr,
                       const float* __restrict__ attS2, const float* __restrict__ attD2,
                       const float* __restrict__ We2, const float* __restrict__ attE2,
                       const unsigned* __restrict__ m2u, float* __restrict__ s2,
                       float* __restrict__ acc2) {
    int stride = gridDim.x * blockDim.x;
    float aS = attS2[0], aD = attD2[0], cE = We2[0] * attE2[0];
    for (int e = blockIdx.x * blockDim.x + threadIdx.x; e < N_EDGES + N_NODES; e += stride) {
        int src, dst;
        float wt;
        if (e < N_EDGES) { src = ei[e]; dst = ei[N_EDGES + e]; wt = w[e]; }
        else             { src = dst = e - N_EDGES; wt = loop_attr[src]; }
        float hs = h2[src];
        float p = expf(leaky(hs * aS + h2[dst] * aD + wt * cE) - kfloat(m2u[dst]));
        atomicAdd(&s2[dst], p);
        atomicAdd(&acc2[dst], p * hs);
    }
}

// ---------- K8: final output ----------
__global__ void k_out(const float* __restrict__ acc2, const float* __restrict__ s2,
                      const float* __restrict__ b2, float* __restrict__ out) {
    int stride = gridDim.x * blockDim.x;
    for (int n = blockIdx.x * blockDim.x + threadIdx.x; n < N_NODES; n += stride)
        out[n] = acc2[n] / (s2[n] + 1e-16f) + b2[0];
}

extern "C" void kernel_launch(void* const* d_in, const int* in_sizes, int n_in,
                              void* d_out, int out_size, void* d_ws, size_t ws_size,
                              hipStream_t stream) {
    const float* x     = (const float*)d_in[0];
    const int*   ei    = (const int*)d_in[1];
    const float* w     = (const float*)d_in[2];
    const float* W1    = (const float*)d_in[3];
    const float* attS1 = (const float*)d_in[4];
    const float* attD1 = (const float*)d_in[5];
    const float* We1   = (const float*)d_in[6];
    const float* attE1 = (const float*)d_in[7];
    const float* b1    = (const float*)d_in[8];
    const float* W2    = (const float*)d_in[9];
    const float* attS2 = (const float*)d_in[10];
    const float* attD2 = (const float*)d_in[11];
    const float* We2   = (const float*)d_in[12];
    const float* attE2 = (const float*)d_in[13];
    const float* b2    = (const float*)d_in[14];
    float* out = (float*)d_out;

    // workspace layout (floats). zero region first: 21*N floats.
    float* ws = (float*)d_ws;
    const size_t N = N_NODES;
    float*    cntf      = ws;                // N
    float*    wsum      = ws + N;            // N
    unsigned* m1u       = (unsigned*)(ws + 2 * N);   // 4N
    float*    s1        = ws + 6 * N;        // 4N
    float*    accX0     = ws + 10 * N;       // 4N
    float*    accX1     = ws + 14 * N;       // 4N
    unsigned* m2u       = (unsigned*)(ws + 18 * N);  // N
    float*    s2        = ws + 19 * N;       // N
    float*    acc2      = ws + 20 * N;       // N
    float*    consts    = ws + 21 * N;       // 32
    float*    loop_attr = ws + 21 * N + 32;  // N
    float*    aS1       = ws + 22 * N + 32;  // 4N
    float*    aD1       = ws + 26 * N + 32;  // 4N
    float*    h2        = ws + 30 * N + 32;  // N

    hipMemsetAsync(d_ws, 0, 21 * N * sizeof(float), stream);

    k_consts<<<1, 32, 0, stream>>>(W1, attS1, attD1, We1, attE1, consts);
    k_degree<<<2048, 256, 0, stream>>>(ei, w, cntf, wsum);
    k_nodeA<<<(N_NODES + 255) / 256, 256, 0, stream>>>(x, consts, cntf, wsum, aS1, aD1, loop_attr);
    k_max1<<<2048, 256, 0, stream>>>(ei, w, aS1, aD1, loop_attr, consts, m1u);
    k_agg1<<<2048, 256, 0, stream>>>(ei, w, x, aS1, aD1, loop_attr, consts, m1u, s1, accX0, accX1);
    k_node2<<<(N_NODES + 255) / 256, 256, 0, stream>>>(accX0, accX1, s1, W1, b1, W2, h2);
    k_max2<<<2048, 256, 0, stream>>>(ei, w, h2, loop_attr, attS2, attD2, We2, attE2, m2u);
    k_sum2<<<2048, 256, 0, stream>>>(ei, w, h2, loop_attr, attS2, attD2, We2, attE2, m2u, s2, acc2);
    k_out<<<(N_NODES + 255) / 256, 256, 0, stream>>>(acc2, s2, b2, out);
}

// Round 2
// 424.702 us; speedup vs baseline: 4.0706x; 4.0706x over previous
//
#include <hip/hip_runtime.h>

#define N_NODES 100000
#define N_EDGES 1600000
#define NEG_SLOPE 0.2f
#define SCAN_B 512

__device__ __forceinline__ float leaky(float v) { return v >= 0.f ? v : NEG_SLOPE * v; }

// ---------- K0: 20 per-head dot constants ----------
// consts[0..7]  : cS1[r][h] = dot(W1[r, h*32:(h+1)*32], attS1[h,:])   (r*4+h)
// consts[8..15] : cD1[r][h] same with attD1
// consts[16..19]: cE1[h]    = dot(We1[0, h*32:(h+1)*32], attE1[h,:])
__global__ void k_consts(const float* __restrict__ W1, const float* __restrict__ attS1,
                         const float* __restrict__ attD1, const float* __restrict__ We1,
                         const float* __restrict__ attE1, float* __restrict__ consts) {
    int t = threadIdx.x;
    if (t < 8) {
        int r = t >> 2, h = t & 3;
        float s = 0.f;
        for (int c = 0; c < 32; ++c) s += W1[r * 128 + h * 32 + c] * attS1[h * 32 + c];
        consts[t] = s;
    } else if (t < 16) {
        int u = t - 8, r = u >> 2, h = u & 3;
        float s = 0.f;
        for (int c = 0; c < 32; ++c) s += W1[r * 128 + h * 32 + c] * attD1[h * 32 + c];
        consts[t] = s;
    } else if (t < 20) {
        int h = t - 16;
        float s = 0.f;
        for (int c = 0; c < 32; ++c) s += We1[h * 32 + c] * attE1[h * 32 + c];
        consts[t] = s;
    }
}

// ---------- K1: in-degree histogram ----------
__global__ void k_count(const int* __restrict__ ei, int* __restrict__ deg) {
    int stride = gridDim.x * blockDim.x;
    for (int e = blockIdx.x * blockDim.x + threadIdx.x; e < N_EDGES; e += stride)
        atomicAdd(&deg[ei[N_EDGES + e]], 1);
}

// ---------- K2a: block-local exclusive scan ----------
__global__ void k_scan1(const int* __restrict__ deg, int* __restrict__ excl,
                        int* __restrict__ bsum) {
    __shared__ int sm[SCAN_B];
    int tid = threadIdx.x;
    int i = blockIdx.x * SCAN_B + tid;
    int v = (i < N_NODES) ? deg[i] : 0;
    sm[tid] = v;
    __syncthreads();
    for (int off = 1; off < SCAN_B; off <<= 1) {
        int t = (tid >= off) ? sm[tid - off] : 0;
        __syncthreads();
        sm[tid] += t;
        __syncthreads();
    }
    if (i < N_NODES) excl[i] = sm[tid] - v;
    if (tid == SCAN_B - 1) bsum[blockIdx.x] = sm[tid];
}

// ---------- K2b: scan the block sums (single block, 256 >= nblocks=196) ----------
__global__ void k_scan2(int* __restrict__ bsum, int nblocks) {
    __shared__ int sm[256];
    int tid = threadIdx.x;
    int v = (tid < nblocks) ? bsum[tid] : 0;
    sm[tid] = v;
    __syncthreads();
    for (int off = 1; off < 256; off <<= 1) {
        int t = (tid >= off) ? sm[tid - off] : 0;
        __syncthreads();
        sm[tid] += t;
        __syncthreads();
    }
    if (tid < nblocks) bsum[tid] = sm[tid] - v;  // exclusive block offset
}

// ---------- K2c: global exclusive prefix -> cursor ----------
__global__ void k_scan3(const int* __restrict__ excl, const int* __restrict__ bsum,
                        int* __restrict__ cursor) {
    int i = blockIdx.x * SCAN_B + threadIdx.x;
    if (i < N_NODES) cursor[i] = excl[i] + bsum[blockIdx.x];
}

// ---------- K3: per-node records: [aS(4), x0, x1, pad, pad] and aD(4) ----------
__global__ void k_nodeA(const float* __restrict__ x, const float* __restrict__ consts,
                        float* __restrict__ nodeRec, float* __restrict__ aD1) {
    int stride = gridDim.x * blockDim.x;
    for (int n = blockIdx.x * blockDim.x + threadIdx.x; n < N_NODES; n += stride) {
        float x0 = x[2 * n], x1 = x[2 * n + 1];
#pragma unroll
        for (int h = 0; h < 4; ++h) {
            nodeRec[n * 8 + h] = x0 * consts[h] + x1 * consts[4 + h];
            aD1[n * 4 + h]     = x0 * consts[8 + h] + x1 * consts[12 + h];
        }
        nodeRec[n * 8 + 4] = x0;
        nodeRec[n * 8 + 5] = x1;
        nodeRec[n * 8 + 6] = 0.f;
        nodeRec[n * 8 + 7] = 0.f;
    }
}

// ---------- K4: CSR scatter (1 atomic/edge) ----------
__global__ void k_scatter(const int* __restrict__ ei, const float* __restrict__ w,
                          int* __restrict__ cursor, int2* __restrict__ csr) {
    int stride = gridDim.x * blockDim.x;
    for (int e = blockIdx.x * blockDim.x + threadIdx.x; e < N_EDGES; e += stride) {
        int dst = ei[N_EDGES + e];
        int pos = atomicAdd(&cursor[dst], 1);
        csr[pos] = make_int2(ei[e], __float_as_int(w[e]));
    }
}

// ---------- K5: layer-1 gather (softmax, linearity-collapsed agg) + node MLP -> h2 ----------
// no segment-max: softmax is shift-invariant; logits bounded (|l| ~< 10)
__global__ void k_gather1(const int* __restrict__ deg, const int* __restrict__ cursor,
                          const int2* __restrict__ csr, const float* __restrict__ nodeRec,
                          const float* __restrict__ aD1, const float* __restrict__ consts,
                          const float* __restrict__ W1, const float* __restrict__ b1,
                          const float* __restrict__ W2, float* __restrict__ h2) {
    __shared__ float w10[128], w11[128], b1s[128], w2s[128];
    for (int j = threadIdx.x; j < 128; j += blockDim.x) {
        w10[j] = W1[j];
        w11[j] = W1[128 + j];
        b1s[j] = b1[j];
        w2s[j] = W2[j];
    }
    __syncthreads();
    float cE[4] = {consts[16], consts[17], consts[18], consts[19]};
    int stride = gridDim.x * blockDim.x;
    for (int n = blockIdx.x * blockDim.x + threadIdx.x; n < N_NODES; n += stride) {
        int end = cursor[n];       // after scatter, cursor = row end
        int d = deg[n];
        int start = end - d;
        float4 ad = *(const float4*)(aD1 + n * 4);
        float adv[4] = {ad.x, ad.y, ad.z, ad.w};
        float s[4] = {0, 0, 0, 0}, X0[4] = {0, 0, 0, 0}, X1[4] = {0, 0, 0, 0};
        float wsum = 0.f;
        for (int k = start; k < end; ++k) {
            int2 rec = csr[k];
            int src = rec.x;
            float wt = __int_as_float(rec.y);
            float4 as = *(const float4*)(nodeRec + src * 8);
            float2 xs = *(const float2*)(nodeRec + src * 8 + 4);
            float asv[4] = {as.x, as.y, as.z, as.w};
            wsum += wt;
#pragma unroll
            for (int h = 0; h < 4; ++h) {
                float p = __expf(leaky(asv[h] + adv[h] + wt * cE[h]));
                s[h] += p;
                X0[h] += p * xs.x;
                X1[h] += p * xs.y;
            }
        }
        // self loop: edge attr = mean incident weight
        float la = wsum / fmaxf((float)d, 1.f);
        float4 aso = *(const float4*)(nodeRec + n * 8);
        float2 xo = *(const float2*)(nodeRec + n * 8 + 4);
        float asov[4] = {aso.x, aso.y, aso.z, aso.w};
#pragma unroll
        for (int h = 0; h < 4; ++h) {
            float p = __expf(leaky(asov[h] + adv[h] + la * cE[h]));
            s[h] += p;
            X0[h] += p * xo.x;
            X1[h] += p * xo.y;
        }
        // reconstruct out1 (128 ch), +b1, ELU, dot with W2 -> scalar h2
        float acc = 0.f;
#pragma unroll
        for (int h = 0; h < 4; ++h) {
            float inv = 1.f / (s[h] + 1e-16f);
            float X0h = X0[h] * inv, X1h = X1[h] * inv;
            for (int c = 0; c < 32; ++c) {
                int j = h * 32 + c;
                float v = X0h * w10[j] + X1h * w11[j] + b1s[j];
                float el = v > 0.f ? v : expm1f(v);
                acc += el * w2s[j];
            }
        }
        h2[n] = acc;
    }
}

// ---------- K6: layer-2 gather -> out ----------
__global__ void k_gather2(const int* __restrict__ deg, const int* __restrict__ cursor,
                          const int2* __restrict__ csr, const float* __restrict__ h2,
                          const float* __restrict__ attS2, const float* __restrict__ attD2,
                          const float* __restrict__ We2, const float* __restrict__ attE2,
                          const float* __restrict__ b2, float* __restrict__ out) {
    float aS = attS2[0], aD = attD2[0], cE = We2[0] * attE2[0], bb = b2[0];
    int stride = gridDim.x * blockDim.x;
    for (int n = blockIdx.x * blockDim.x + threadIdx.x; n < N_NODES; n += stride) {
        int end = cursor[n];
        int d = deg[n];
        int start = end - d;
        float hn = h2[n];
        float hnaD = hn * aD;
        float s = 0.f, acc = 0.f, wsum = 0.f;
        for (int k = start; k < end; ++k) {
            int2 rec = csr[k];
            float hs = h2[rec.x];
            float wt = __int_as_float(rec.y);
            wsum += wt;
            float p = __expf(leaky(hs * aS + hnaD + wt * cE));
            s += p;
            acc += p * hs;
        }
        float la = wsum / fmaxf((float)d, 1.f);
        float p = __expf(leaky(hn * aS + hnaD + la * cE));
        s += p;
        acc += p * hn;
        out[n] = acc / (s + 1e-16f) + bb;
    }
}

extern "C" void kernel_launch(void* const* d_in, const int* in_sizes, int n_in,
                              void* d_out, int out_size, void* d_ws, size_t ws_size,
                              hipStream_t stream) {
    const float* x     = (const float*)d_in[0];
    const int*   ei    = (const int*)d_in[1];
    const float* w     = (const float*)d_in[2];
    const float* W1    = (const float*)d_in[3];
    const float* attS1 = (const float*)d_in[4];
    const float* attD1 = (const float*)d_in[5];
    const float* We1   = (const float*)d_in[6];
    const float* attE1 = (const float*)d_in[7];
    const float* b1    = (const float*)d_in[8];
    const float* W2    = (const float*)d_in[9];
    const float* attS2 = (const float*)d_in[10];
    const float* attD2 = (const float*)d_in[11];
    const float* We2   = (const float*)d_in[12];
    const float* attE2 = (const float*)d_in[13];
    const float* b2    = (const float*)d_in[14];
    float* out = (float*)d_out;

    const int N = N_NODES;
    const int nblocks1 = (N + SCAN_B - 1) / SCAN_B;  // 196

    // workspace layout
    int*   deg    = (int*)d_ws;                 // N
    int*   excl   = deg + N;                    // N
    int*   bsum   = excl + N;                   // 256
    int*   cursor = bsum + 256;                 // N
    int2*  csr    = (int2*)(cursor + N);        // E int2 (offset 3N+256 ints, 8B-aligned)
    float* nodeRec = (float*)(csr + N_EDGES);   // 8N floats (32B-aligned)
    float* aD1    = nodeRec + 8 * (size_t)N;    // 4N
    float* consts = aD1 + 4 * (size_t)N;        // 32
    float* h2     = consts + 32;                // N

    hipMemsetAsync(deg, 0, N * sizeof(int), stream);

    k_consts<<<1, 32, 0, stream>>>(W1, attS1, attD1, We1, attE1, consts);
    k_count<<<2048, 256, 0, stream>>>(ei, deg);
    k_scan1<<<nblocks1, SCAN_B, 0, stream>>>(deg, excl, bsum);
    k_scan2<<<1, 256, 0, stream>>>(bsum, nblocks1);
    k_scan3<<<nblocks1, SCAN_B, 0, stream>>>(excl, bsum, cursor);
    k_nodeA<<<(N + 255) / 256, 256, 0, stream>>>(x, consts, nodeRec, aD1);
    k_scatter<<<2048, 256, 0, stream>>>(ei, w, cursor, csr);
    k_gather1<<<(N + 255) / 256, 256, 0, stream>>>(deg, cursor, csr, nodeRec, aD1, consts,
                                                   W1, b1, W2, h2);
    k_gather2<<<(N + 255) / 256, 256, 0, stream>>>(deg, cursor, csr, h2, attS2, attD2,
                                                   We2, attE2, b2, out);
}

// Round 3
// 304.620 us; speedup vs baseline: 5.6752x; 1.3942x over previous
//
#include <hip/hip_runtime.h>

#define N_NODES 100000
#define N_EDGES 1600000
#define NEG_SLOPE 0.2f
#define SCAN_B 512

__device__ __forceinline__ float leaky(float v) { return v >= 0.f ? v : NEG_SLOPE * v; }

// ---------- K1: in-degree histogram (int4-vectorized: 4 edges/thread) ----------
__global__ void k_count(const int* __restrict__ ei, int* __restrict__ deg) {
    const int4* dst4 = (const int4*)(ei + N_EDGES);
    int stride = gridDim.x * blockDim.x;
    for (int i = blockIdx.x * blockDim.x + threadIdx.x; i < N_EDGES / 4; i += stride) {
        int4 d = dst4[i];
        atomicAdd(&deg[d.x], 1);
        atomicAdd(&deg[d.y], 1);
        atomicAdd(&deg[d.z], 1);
        atomicAdd(&deg[d.w], 1);
    }
}

// ---------- K2a: block-local exclusive scan ----------
__global__ void k_scan1(const int* __restrict__ deg, int* __restrict__ excl,
                        int* __restrict__ bsum) {
    __shared__ int sm[SCAN_B];
    int tid = threadIdx.x;
    int i = blockIdx.x * SCAN_B + tid;
    int v = (i < N_NODES) ? deg[i] : 0;
    sm[tid] = v;
    __syncthreads();
    for (int off = 1; off < SCAN_B; off <<= 1) {
        int t = (tid >= off) ? sm[tid - off] : 0;
        __syncthreads();
        sm[tid] += t;
        __syncthreads();
    }
    if (i < N_NODES) excl[i] = sm[tid] - v;
    if (tid == SCAN_B - 1) bsum[blockIdx.x] = sm[tid];
}

// ---------- K2b: scan block sums (1 block) + fused: 20 attention dot-constants ----------
// consts[0..7]  cS1[r][h]; consts[8..15] cD1[r][h]; consts[16..19] cE1[h]
__global__ void k_scan2c(int* __restrict__ bsum, int nblocks, const float* __restrict__ W1,
                         const float* __restrict__ attS1, const float* __restrict__ attD1,
                         const float* __restrict__ We1, const float* __restrict__ attE1,
                         float* __restrict__ consts) {
    __shared__ int sm[256];
    int tid = threadIdx.x;
    // fused consts computation (threads 0..19)
    if (tid < 8) {
        int r = tid >> 2, h = tid & 3;
        float s = 0.f;
        for (int c = 0; c < 32; ++c) s += W1[r * 128 + h * 32 + c] * attS1[h * 32 + c];
        consts[tid] = s;
    } else if (tid < 16) {
        int u = tid - 8, r = u >> 2, h = u & 3;
        float s = 0.f;
        for (int c = 0; c < 32; ++c) s += W1[r * 128 + h * 32 + c] * attD1[h * 32 + c];
        consts[tid] = s;
    } else if (tid < 20) {
        int h = tid - 16;
        float s = 0.f;
        for (int c = 0; c < 32; ++c) s += We1[h * 32 + c] * attE1[h * 32 + c];
        consts[tid] = s;
    }
    int v = (tid < nblocks) ? bsum[tid] : 0;
    sm[tid] = v;
    __syncthreads();
    for (int off = 1; off < 256; off <<= 1) {
        int t = (tid >= off) ? sm[tid - off] : 0;
        __syncthreads();
        sm[tid] += t;
        __syncthreads();
    }
    if (tid < nblocks) bsum[tid] = sm[tid] - v;  // exclusive block offset
}

// ---------- K2c: global prefix -> cursor, fused with per-node records ----------
// nodeRec[n*8..] = [aS(4), x0, x1, pad, pad]; aD1[n*4..] = aD(4)
__global__ void k_scan3n(const int* __restrict__ excl, const int* __restrict__ bsum,
                         int* __restrict__ cursor, const float* __restrict__ x,
                         const float* __restrict__ consts, float* __restrict__ nodeRec,
                         float* __restrict__ aD1) {
    int n = blockIdx.x * SCAN_B + threadIdx.x;
    if (n >= N_NODES) return;
    cursor[n] = excl[n] + bsum[blockIdx.x];
    float x0 = x[2 * n], x1 = x[2 * n + 1];
#pragma unroll
    for (int h = 0; h < 4; ++h) {
        nodeRec[n * 8 + h] = x0 * consts[h] + x1 * consts[4 + h];
        aD1[n * 4 + h]     = x0 * consts[8 + h] + x1 * consts[12 + h];
    }
    nodeRec[n * 8 + 4] = x0;
    nodeRec[n * 8 + 5] = x1;
    nodeRec[n * 8 + 6] = 0.f;
    nodeRec[n * 8 + 7] = 0.f;
}

// ---------- K4: CSR scatter (vectorized reads, 1 atomic/edge) ----------
__global__ void k_scatter(const int* __restrict__ ei, const float* __restrict__ w,
                          int* __restrict__ cursor, int2* __restrict__ csr) {
    const int4* src4 = (const int4*)ei;
    const int4* dst4 = (const int4*)(ei + N_EDGES);
    const float4* w4 = (const float4*)w;
    int stride = gridDim.x * blockDim.x;
    for (int i = blockIdx.x * blockDim.x + threadIdx.x; i < N_EDGES / 4; i += stride) {
        int4 s = src4[i];
        int4 d = dst4[i];
        float4 ww = w4[i];
        int p;
        p = atomicAdd(&cursor[d.x], 1); csr[p] = make_int2(s.x, __float_as_int(ww.x));
        p = atomicAdd(&cursor[d.y], 1); csr[p] = make_int2(s.y, __float_as_int(ww.y));
        p = atomicAdd(&cursor[d.z], 1); csr[p] = make_int2(s.z, __float_as_int(ww.z));
        p = atomicAdd(&cursor[d.w], 1); csr[p] = make_int2(s.w, __float_as_int(ww.w));
    }
}

// ---------- K5: layer-1 gather, 4 lanes/node edge-split + fused node MLP -> h2 ----------
__global__ void k_gather1(const int* __restrict__ deg, const int* __restrict__ cursor,
                          const int2* __restrict__ csr, const float* __restrict__ nodeRec,
                          const float* __restrict__ aD1, const float* __restrict__ consts,
                          const float* __restrict__ W1, const float* __restrict__ b1,
                          const float* __restrict__ W2, float* __restrict__ h2) {
    // stride-33 padding kills the 4-way bank conflict of j = h*32+c
    __shared__ float w10[132], w11[132], b1s[132], w2s[132];
    for (int j = threadIdx.x; j < 128; j += blockDim.x) {
        int jj = (j >> 5) * 33 + (j & 31);
        w10[jj] = W1[j];
        w11[jj] = W1[128 + j];
        b1s[jj] = b1[j];
        w2s[jj] = W2[j];
    }
    __syncthreads();
    int t = blockIdx.x * blockDim.x + threadIdx.x;
    int n = t >> 2, l = t & 3;
    if (n >= N_NODES) return;
    float cE[4] = {consts[16], consts[17], consts[18], consts[19]};
    int end = cursor[n];
    int d = deg[n];
    int start = end - d;
    float4 ad = *(const float4*)(aD1 + n * 4);
    float adv[4] = {ad.x, ad.y, ad.z, ad.w};
    float s[4] = {0, 0, 0, 0}, X0[4] = {0, 0, 0, 0}, X1[4] = {0, 0, 0, 0};
    float wsum = 0.f;
    for (int k = start + l; k < end; k += 4) {
        int2 rec = csr[k];
        int src = rec.x;
        float wt = __int_as_float(rec.y);
        float4 as = *(const float4*)(nodeRec + src * 8);
        float2 xs = *(const float2*)(nodeRec + src * 8 + 4);
        float asv[4] = {as.x, as.y, as.z, as.w};
        wsum += wt;
#pragma unroll
        for (int h = 0; h < 4; ++h) {
            float p = __expf(leaky(asv[h] + adv[h] + wt * cE[h]));
            s[h] += p;
            X0[h] += p * xs.x;
            X1[h] += p * xs.y;
        }
    }
    // reduce the 13 partials across the aligned 4-lane group
#pragma unroll
    for (int off = 1; off < 4; off <<= 1) {
        wsum += __shfl_xor(wsum, off);
#pragma unroll
        for (int h = 0; h < 4; ++h) {
            s[h]  += __shfl_xor(s[h], off);
            X0[h] += __shfl_xor(X0[h], off);
            X1[h] += __shfl_xor(X1[h], off);
        }
    }
    // self loop (all 4 lanes redundantly): edge attr = mean incident weight
    float la = wsum / fmaxf((float)d, 1.f);
    float4 aso = *(const float4*)(nodeRec + n * 8);
    float2 xo = *(const float2*)(nodeRec + n * 8 + 4);
    float asov[4] = {aso.x, aso.y, aso.z, aso.w};
#pragma unroll
    for (int h = 0; h < 4; ++h) {
        float p = __expf(leaky(asov[h] + adv[h] + la * cE[h]));
        s[h] += p;
        X0[h] += p * xo.x;
        X1[h] += p * xo.y;
    }
    // MLP tail: lane l takes head l (avoid runtime-indexed reg arrays: select chain)
    float sh  = (l == 0) ? s[0]  : (l == 1) ? s[1]  : (l == 2) ? s[2]  : s[3];
    float X0h = (l == 0) ? X0[0] : (l == 1) ? X0[1] : (l == 2) ? X0[2] : X0[3];
    float X1h = (l == 0) ? X1[0] : (l == 1) ? X1[1] : (l == 2) ? X1[2] : X1[3];
    float inv = 1.f / (sh + 1e-16f);
    X0h *= inv;
    X1h *= inv;
    float acc = 0.f;
    int base = l * 33;
    for (int c = 0; c < 32; ++c) {
        float v = X0h * w10[base + c] + X1h * w11[base + c] + b1s[base + c];
        float el = v > 0.f ? v : __expf(v) - 1.f;  // elu; exp(v)<=1 so abs err ~1e-7
        acc += el * w2s[base + c];
    }
    acc += __shfl_xor(acc, 1);
    acc += __shfl_xor(acc, 2);
    if (l == 0) h2[n] = acc;
}

// ---------- K6: layer-2 gather, 4 lanes/node edge-split -> out ----------
__global__ void k_gather2(const int* __restrict__ deg, const int* __restrict__ cursor,
                          const int2* __restrict__ csr, const float* __restrict__ h2,
                          const float* __restrict__ attS2, const float* __restrict__ attD2,
                          const float* __restrict__ We2, const float* __restrict__ attE2,
                          const float* __restrict__ b2, float* __restrict__ out) {
    int t = blockIdx.x * blockDim.x + threadIdx.x;
    int n = t >> 2, l = t & 3;
    if (n >= N_NODES) return;
    float aS = attS2[0], aD = attD2[0], cE = We2[0] * attE2[0], bb = b2[0];
    int end = cursor[n];
    int d = deg[n];
    int start = end - d;
    float hn = h2[n];
    float hnaD = hn * aD;
    float s = 0.f, acc = 0.f, wsum = 0.f;
    for (int k = start + l; k < end; k += 4) {
        int2 rec = csr[k];
        float hs = h2[rec.x];
        float wt = __int_as_float(rec.y);
        wsum += wt;
        float p = __expf(leaky(hs * aS + hnaD + wt * cE));
        s += p;
        acc += p * hs;
    }
#pragma unroll
    for (int off = 1; off < 4; off <<= 1) {
        wsum += __shfl_xor(wsum, off);
        s    += __shfl_xor(s, off);
        acc  += __shfl_xor(acc, off);
    }
    float la = wsum / fmaxf((float)d, 1.f);
    float p = __expf(leaky(hn * aS + hnaD + la * cE));
    s += p;
    acc += p * hn;
    if (l == 0) out[n] = acc / (s + 1e-16f) + bb;
}

extern "C" void kernel_launch(void* const* d_in, const int* in_sizes, int n_in,
                              void* d_out, int out_size, void* d_ws, size_t ws_size,
                              hipStream_t stream) {
    const float* x     = (const float*)d_in[0];
    const int*   ei    = (const int*)d_in[1];
    const float* w     = (const float*)d_in[2];
    const float* W1    = (const float*)d_in[3];
    const float* attS1 = (const float*)d_in[4];
    const float* attD1 = (const float*)d_in[5];
    const float* We1   = (const float*)d_in[6];
    const float* attE1 = (const float*)d_in[7];
    const float* b1    = (const float*)d_in[8];
    const float* W2    = (const float*)d_in[9];
    const float* attS2 = (const float*)d_in[10];
    const float* attD2 = (const float*)d_in[11];
    const float* We2   = (const float*)d_in[12];
    const float* attE2 = (const float*)d_in[13];
    const float* b2    = (const float*)d_in[14];
    float* out = (float*)d_out;

    const int N = N_NODES;
    const int nblocks1 = (N + SCAN_B - 1) / SCAN_B;  // 196

    // workspace layout
    int*   deg    = (int*)d_ws;                 // N
    int*   excl   = deg + N;                    // N
    int*   bsum   = excl + N;                   // 256
    int*   cursor = bsum + 256;                 // N
    int2*  csr    = (int2*)(cursor + N);        // E int2
    float* nodeRec = (float*)(csr + N_EDGES);   // 8N
    float* aD1    = nodeRec + 8 * (size_t)N;    // 4N
    float* consts = aD1 + 4 * (size_t)N;        // 32
    float* h2     = consts + 32;                // N

    hipMemsetAsync(deg, 0, N * sizeof(int), stream);

    k_count<<<1024, 256, 0, stream>>>(ei, deg);
    k_scan1<<<nblocks1, SCAN_B, 0, stream>>>(deg, excl, bsum);
    k_scan2c<<<1, 256, 0, stream>>>(bsum, nblocks1, W1, attS1, attD1, We1, attE1, consts);
    k_scan3n<<<nblocks1, SCAN_B, 0, stream>>>(excl, bsum, cursor, x, consts, nodeRec, aD1);
    k_scatter<<<1024, 256, 0, stream>>>(ei, w, cursor, csr);
    k_gather1<<<(4 * N + 255) / 256, 256, 0, stream>>>(deg, cursor, csr, nodeRec, aD1,
                                                       consts, W1, b1, W2, h2);
    k_gather2<<<(4 * N + 255) / 256, 256, 0, stream>>>(deg, cursor, csr, h2, attS2, attD2,
                                                       We2, attE2, b2, out);
}

// Round 5
// 281.809 us; speedup vs baseline: 6.1346x; 1.0809x over previous
//
#include <hip/hip_runtime.h>

#define N_NODES 100000
#define N_EDGES 1600000
#define NEG_SLOPE 0.2f
#define SCAN_B 512
#define NGRP 8
#define GRP_SZ (N_NODES / NGRP)   // 12500 exactly

// clang ext-vector types: __builtin_nontemporal_load needs real vector types,
// not HIP's struct wrappers.
typedef int   vint4  __attribute__((ext_vector_type(4)));
typedef int   vint2  __attribute__((ext_vector_type(2)));
typedef float vfloat4 __attribute__((ext_vector_type(4)));

__device__ __forceinline__ float leaky(float v) { return v >= 0.f ? v : NEG_SLOPE * v; }

// ---------- K1: in-degree histogram (int4-vectorized, nt loads) ----------
__global__ void k_count(const int* __restrict__ ei, int* __restrict__ deg) {
    const vint4* dst4 = (const vint4*)(ei + N_EDGES);
    int stride = gridDim.x * blockDim.x;
    for (int i = blockIdx.x * blockDim.x + threadIdx.x; i < N_EDGES / 4; i += stride) {
        vint4 d = __builtin_nontemporal_load(&dst4[i]);
        atomicAdd(&deg[d.x], 1);
        atomicAdd(&deg[d.y], 1);
        atomicAdd(&deg[d.z], 1);
        atomicAdd(&deg[d.w], 1);
    }
}

// ---------- K2a: block-local exclusive scan ----------
__global__ void k_scan1(const int* __restrict__ deg, int* __restrict__ excl,
                        int* __restrict__ bsum) {
    __shared__ int sm[SCAN_B];
    int tid = threadIdx.x;
    int i = blockIdx.x * SCAN_B + tid;
    int v = (i < N_NODES) ? deg[i] : 0;
    sm[tid] = v;
    __syncthreads();
    for (int off = 1; off < SCAN_B; off <<= 1) {
        int t = (tid >= off) ? sm[tid - off] : 0;
        __syncthreads();
        sm[tid] += t;
        __syncthreads();
    }
    if (i < N_NODES) excl[i] = sm[tid] - v;
    if (tid == SCAN_B - 1) bsum[blockIdx.x] = sm[tid];
}

// ---------- K2b: scan block sums (1 block) + fused attention dot-constants ----------
__global__ void k_scan2c(int* __restrict__ bsum, int nblocks, const float* __restrict__ W1,
                         const float* __restrict__ attS1, const float* __restrict__ attD1,
                         const float* __restrict__ We1, const float* __restrict__ attE1,
                         float* __restrict__ consts) {
    __shared__ int sm[256];
    int tid = threadIdx.x;
    if (tid < 8) {
        int r = tid >> 2, h = tid & 3;
        float s = 0.f;
        for (int c = 0; c < 32; ++c) s += W1[r * 128 + h * 32 + c] * attS1[h * 32 + c];
        consts[tid] = s;
    } else if (tid < 16) {
        int u = tid - 8, r = u >> 2, h = u & 3;
        float s = 0.f;
        for (int c = 0; c < 32; ++c) s += W1[r * 128 + h * 32 + c] * attD1[h * 32 + c];
        consts[tid] = s;
    } else if (tid < 20) {
        int h = tid - 16;
        float s = 0.f;
        for (int c = 0; c < 32; ++c) s += We1[h * 32 + c] * attE1[h * 32 + c];
        consts[tid] = s;
    }
    int v = (tid < nblocks) ? bsum[tid] : 0;
    sm[tid] = v;
    __syncthreads();
    for (int off = 1; off < 256; off <<= 1) {
        int t = (tid >= off) ? sm[tid - off] : 0;
        __syncthreads();
        sm[tid] += t;
        __syncthreads();
    }
    if (tid < nblocks) bsum[tid] = sm[tid] - v;
}

// ---------- K2c: global prefix -> cursor, fused per-node records ----------
__global__ void k_scan3n(const int* __restrict__ excl, const int* __restrict__ bsum,
                         int* __restrict__ cursor, const float* __restrict__ x,
                         const float* __restrict__ consts, float* __restrict__ nodeRec,
                         float* __restrict__ aD1) {
    int n = blockIdx.x * SCAN_B + threadIdx.x;
    if (n >= N_NODES) return;
    cursor[n] = excl[n] + bsum[blockIdx.x];
    float x0 = x[2 * n], x1 = x[2 * n + 1];
#pragma unroll
    for (int h = 0; h < 4; ++h) {
        nodeRec[n * 8 + h] = x0 * consts[h] + x1 * consts[4 + h];
        aD1[n * 4 + h]     = x0 * consts[8 + h] + x1 * consts[12 + h];
    }
    nodeRec[n * 8 + 4] = x0;
    nodeRec[n * 8 + 5] = x1;
    nodeRec[n * 8 + 6] = 0.f;
    nodeRec[n * 8 + 7] = 0.f;
}

// ---------- K4: dst-range-grouped CSR scatter ----------
// group g = blockIdx&7 handles dsts in [g*GRP_SZ, (g+1)*GRP_SZ): csr slice
// ~1.6MB stays in one XCD's L2 so 8B writes combine before eviction.
__global__ void k_scatter(const int* __restrict__ ei, const float* __restrict__ w,
                          int* __restrict__ cursor, int2* __restrict__ csr) {
    const vint4* src4 = (const vint4*)ei;
    const vint4* dst4 = (const vint4*)(ei + N_EDGES);
    const vfloat4* w4 = (const vfloat4*)w;
    int grp = blockIdx.x & (NGRP - 1);
    int lo = grp * GRP_SZ, hi = lo + GRP_SZ;
    int bi = blockIdx.x >> 3;
    int nb = gridDim.x >> 3;
    int stride = nb * blockDim.x;
    for (int i = bi * blockDim.x + threadIdx.x; i < N_EDGES / 4; i += stride) {
        vint4 d = __builtin_nontemporal_load(&dst4[i]);
        if ((d.x < lo || d.x >= hi) && (d.y < lo || d.y >= hi) &&
            (d.z < lo || d.z >= hi) && (d.w < lo || d.w >= hi)) continue;
        vint4 s = __builtin_nontemporal_load(&src4[i]);
        vfloat4 ww = __builtin_nontemporal_load(&w4[i]);
        int p;
        if (d.x >= lo && d.x < hi) { p = atomicAdd(&cursor[d.x], 1); csr[p] = make_int2(s.x, __float_as_int(ww.x)); }
        if (d.y >= lo && d.y < hi) { p = atomicAdd(&cursor[d.y], 1); csr[p] = make_int2(s.y, __float_as_int(ww.y)); }
        if (d.z >= lo && d.z < hi) { p = atomicAdd(&cursor[d.z], 1); csr[p] = make_int2(s.z, __float_as_int(ww.z)); }
        if (d.w >= lo && d.w < hi) { p = atomicAdd(&cursor[d.w], 1); csr[p] = make_int2(s.w, __float_as_int(ww.w)); }
    }
}

// ---------- K5: layer-1 gather, 8 lanes/node + fused node MLP -> h2 ----------
__global__ void k_gather1(const int* __restrict__ deg, const int* __restrict__ cursor,
                          const int2* __restrict__ csr, const float* __restrict__ nodeRec,
                          const float* __restrict__ aD1, const float* __restrict__ consts,
                          const float* __restrict__ W1, const float* __restrict__ b1,
                          const float* __restrict__ W2, float* __restrict__ h2) {
    // stride-33 padding kills bank conflicts for j = h*32+c access
    __shared__ float w10[132], w11[132], b1s[132], w2s[132];
    for (int j = threadIdx.x; j < 128; j += blockDim.x) {
        int jj = (j >> 5) * 33 + (j & 31);
        w10[jj] = W1[j];
        w11[jj] = W1[128 + j];
        b1s[jj] = b1[j];
        w2s[jj] = W2[j];
    }
    __syncthreads();
    int t = blockIdx.x * blockDim.x + threadIdx.x;
    int n = t >> 3, l = t & 7;
    if (n >= N_NODES) return;
    float cE[4] = {consts[16], consts[17], consts[18], consts[19]};
    int end = cursor[n];
    int d = deg[n];
    int start = end - d;
    float4 ad = *(const float4*)(aD1 + n * 4);
    float adv[4] = {ad.x, ad.y, ad.z, ad.w};
    float s[4] = {0, 0, 0, 0}, X0[4] = {0, 0, 0, 0}, X1[4] = {0, 0, 0, 0};
    float wsum = 0.f;
    const vint2* csr2 = (const vint2*)csr;
    for (int k = start + l; k < end; k += 8) {
        vint2 rec = __builtin_nontemporal_load(&csr2[k]);
        int src = rec.x;
        float wt = __int_as_float(rec.y);
        float4 as = *(const float4*)(nodeRec + src * 8);
        float2 xs = *(const float2*)(nodeRec + src * 8 + 4);
        float asv[4] = {as.x, as.y, as.z, as.w};
        wsum += wt;
#pragma unroll
        for (int h = 0; h < 4; ++h) {
            float p = __expf(leaky(asv[h] + adv[h] + wt * cE[h]));
            s[h] += p;
            X0[h] += p * xs.x;
            X1[h] += p * xs.y;
        }
    }
    // reduce 14 partials across the aligned 8-lane group
#pragma unroll
    for (int off = 1; off < 8; off <<= 1) {
        wsum += __shfl_xor(wsum, off);
#pragma unroll
        for (int h = 0; h < 4; ++h) {
            s[h]  += __shfl_xor(s[h], off);
            X0[h] += __shfl_xor(X0[h], off);
            X1[h] += __shfl_xor(X1[h], off);
        }
    }
    // self loop (redundant on all lanes): edge attr = mean incident weight
    float la = wsum / fmaxf((float)d, 1.f);
    float4 aso = *(const float4*)(nodeRec + n * 8);
    float2 xo = *(const float2*)(nodeRec + n * 8 + 4);
    float asov[4] = {aso.x, aso.y, aso.z, aso.w};
#pragma unroll
    for (int h = 0; h < 4; ++h) {
        float p = __expf(leaky(asov[h] + adv[h] + la * cE[h]));
        s[h] += p;
        X0[h] += p * xo.x;
        X1[h] += p * xo.y;
    }
    // MLP tail: lane l -> head l&3, channel-half l>>2 (16 ch each)
    int hh = l & 3;
    float sh  = (hh == 0) ? s[0]  : (hh == 1) ? s[1]  : (hh == 2) ? s[2]  : s[3];
    float X0h = (hh == 0) ? X0[0] : (hh == 1) ? X0[1] : (hh == 2) ? X0[2] : X0[3];
    float X1h = (hh == 0) ? X1[0] : (hh == 1) ? X1[1] : (hh == 2) ? X1[2] : X1[3];
    float inv = 1.f / (sh + 1e-16f);
    X0h *= inv;
    X1h *= inv;
    float acc = 0.f;
    int base = hh * 33 + (l >> 2) * 16;
    for (int c = 0; c < 16; ++c) {
        float v = X0h * w10[base + c] + X1h * w11[base + c] + b1s[base + c];
        float el = v > 0.f ? v : __expf(v) - 1.f;  // elu
        acc += el * w2s[base + c];
    }
    acc += __shfl_xor(acc, 1);
    acc += __shfl_xor(acc, 2);
    acc += __shfl_xor(acc, 4);
    if (l == 0) h2[n] = acc;
}

// ---------- K6: layer-2 gather, 8 lanes/node -> out ----------
__global__ void k_gather2(const int* __restrict__ deg, const int* __restrict__ cursor,
                          const int2* __restrict__ csr, const float* __restrict__ h2,
                          const float* __restrict__ attS2, const float* __restrict__ attD2,
                          const float* __restrict__ We2, const float* __restrict__ attE2,
                          const float* __restrict__ b2, float* __restrict__ out) {
    int t = blockIdx.x * blockDim.x + threadIdx.x;
    int n = t >> 3, l = t & 7;
    if (n >= N_NODES) return;
    float aS = attS2[0], aD = attD2[0], cE = We2[0] * attE2[0], bb = b2[0];
    int end = cursor[n];
    int d = deg[n];
    int start = end - d;
    float hn = h2[n];
    float hnaD = hn * aD;
    float s = 0.f, acc = 0.f, wsum = 0.f;
    const vint2* csr2 = (const vint2*)csr;
    for (int k = start + l; k < end; k += 8) {
        vint2 rec = __builtin_nontemporal_load(&csr2[k]);
        float hs = h2[rec.x];
        float wt = __int_as_float(rec.y);
        wsum += wt;
        float p = __expf(leaky(hs * aS + hnaD + wt * cE));
        s += p;
        acc += p * hs;
    }
#pragma unroll
    for (int off = 1; off < 8; off <<= 1) {
        wsum += __shfl_xor(wsum, off);
        s    += __shfl_xor(s, off);
        acc  += __shfl_xor(acc, off);
    }
    float la = wsum / fmaxf((float)d, 1.f);
    float p = __expf(leaky(hn * aS + hnaD + la * cE));
    s += p;
    acc += p * hn;
    if (l == 0) out[n] = acc / (s + 1e-16f) + bb;
}

extern "C" void kernel_launch(void* const* d_in, const int* in_sizes, int n_in,
                              void* d_out, int out_size, void* d_ws, size_t ws_size,
                              hipStream_t stream) {
    const float* x     = (const float*)d_in[0];
    const int*   ei    = (const int*)d_in[1];
    const float* w     = (const float*)d_in[2];
    const float* W1    = (const float*)d_in[3];
    const float* attS1 = (const float*)d_in[4];
    const float* attD1 = (const float*)d_in[5];
    const float* We1   = (const float*)d_in[6];
    const float* attE1 = (const float*)d_in[7];
    const float* b1    = (const float*)d_in[8];
    const float* W2    = (const float*)d_in[9];
    const float* attS2 = (const float*)d_in[10];
    const float* attD2 = (const float*)d_in[11];
    const float* We2   = (const float*)d_in[12];
    const float* attE2 = (const float*)d_in[13];
    const float* b2    = (const float*)d_in[14];
    float* out = (float*)d_out;

    const int N = N_NODES;
    const int nblocks1 = (N + SCAN_B - 1) / SCAN_B;  // 196

    // workspace layout
    int*   deg    = (int*)d_ws;                 // N
    int*   excl   = deg + N;                    // N
    int*   bsum   = excl + N;                   // 256
    int*   cursor = bsum + 256;                 // N
    int2*  csr    = (int2*)(cursor + N);        // E int2
    float* nodeRec = (float*)(csr + N_EDGES);   // 8N
    float* aD1    = nodeRec + 8 * (size_t)N;    // 4N
    float* consts = aD1 + 4 * (size_t)N;        // 32
    float* h2     = consts + 32;                // N

    (void)hipMemsetAsync(deg, 0, N * sizeof(int), stream);

    k_count<<<2048, 256, 0, stream>>>(ei, deg);
    k_scan1<<<nblocks1, SCAN_B, 0, stream>>>(deg, excl, bsum);
    k_scan2c<<<1, 256, 0, stream>>>(bsum, nblocks1, W1, attS1, attD1, We1, attE1, consts);
    k_scan3n<<<nblocks1, SCAN_B, 0, stream>>>(excl, bsum, cursor, x, consts, nodeRec, aD1);
    k_scatter<<<2048, 256, 0, stream>>>(ei, w, cursor, csr);
    k_gather1<<<(8 * N + 255) / 256, 256, 0, stream>>>(deg, cursor, csr, nodeRec, aD1,
                                                       consts, W1, b1, W2, h2);
    k_gather2<<<(8 * N + 255) / 256, 256, 0, stream>>>(deg, cursor, csr, h2, attS2, attD2,
                                                       We2, attE2, b2, out);
}